// Round 8
// baseline (53.261 us; speedup 1.0000x reference)
//
#include <hip/hip_runtime.h>

#define D  128   // EMB
#define KN 128   // K_N
#define NB 16    // batch rows per block
#define LOG2E 1.44269504088896340736f

typedef float f32x4  __attribute__((ext_vector_type(4)));
typedef float f32x16 __attribute__((ext_vector_type(16)));
typedef short s16x8  __attribute__((ext_vector_type(8)));   // 8 bf16 (4 VGPR)

__device__ __forceinline__ float negexp(float v) {              // e^{-v}
    return __builtin_amdgcn_exp2f(v * -LOG2E);
}
__device__ __forceinline__ float sigf(float x) {                // sigmoid
    return __builtin_amdgcn_rcpf(1.0f + negexp(x));
}
__device__ __forceinline__ unsigned short f2bf(float f) {       // fp32->bf16 RNE
    unsigned u = __float_as_uint(f);
    return (unsigned short)((u + 0x7fffu + ((u >> 16) & 1u)) >> 16);
}
__device__ __forceinline__ s16x8 pack8(float4 a, float4 b) {
    s16x8 r;
    r[0]=(short)f2bf(a.x); r[1]=(short)f2bf(a.y); r[2]=(short)f2bf(a.z); r[3]=(short)f2bf(a.w);
    r[4]=(short)f2bf(b.x); r[5]=(short)f2bf(b.y); r[6]=(short)f2bf(b.z); r[7]=(short)f2bf(b.w);
    return r;
}
__device__ __forceinline__ s16x8 pack8abs(float4 a, float4 b) {
    s16x8 r;
    r[0]=(short)f2bf(fabsf(a.x)); r[1]=(short)f2bf(fabsf(a.y)); r[2]=(short)f2bf(fabsf(a.z)); r[3]=(short)f2bf(fabsf(a.w));
    r[4]=(short)f2bf(fabsf(b.x)); r[5]=(short)f2bf(fabsf(b.y)); r[6]=(short)f2bf(fabsf(b.z)); r[7]=(short)f2bf(fabsf(b.w));
    return r;
}
// uniform-lane register broadcast (VALU pipe, not LDS)
__device__ __forceinline__ float rl(float v, int srcLane) {
    return __uint_as_float(__builtin_amdgcn_readlane(__float_as_uint(v), srcLane));
}

// phase-B core: 2 elements (k=2l,2l+1) of one (b,e)
#define CORE(EA1, EA2, T, PZ, A0, A1) do {                                   \
    float x0_ = fmaf((EA1), (T).x, 1.0f);                                    \
    float x1_ = fmaf((EA1), (T).y, 1.0f);                                    \
    float y0_ = fmaf((EA2), (T).z, 1.0f);                                    \
    float y1_ = fmaf((EA2), (T).w, 1.0f);                                    \
    (A0) = fmaf((y0_ - x0_) * (PZ), __builtin_amdgcn_rcpf(x0_ * y0_), (A0)); \
    (A1) = fmaf((y1_ - x1_) * (PZ), __builtin_amdgcn_rcpf(x1_ * y1_), (A1)); \
} while (0)

// tables write: exp(-(acc+bias)) into interleaved TAB layout
//   TABf[e*256 + (k>>1)*4 + (k&1) + (0|2)]
#define TWRITE(T, ACC) {                                                      \
    const int idx_ = (wid << 2) + (T);                                        \
    const int et_ = (idx_ >> 2) & 3, kt_ = idx_ & 3;                          \
    const int slot_ = (idx_ < 16) ? 0 : 2;                                    \
    const float* bias_ = (idx_ < 16) ? b1 : b2;                               \
    const int k_ = kt_ * 32 + l31;                                            \
    const int kof_ = ((k_ >> 1) << 2) + (k_ & 1) + slot_;                     \
    _Pragma("unroll")                                                         \
    for (int r = 0; r < 16; ++r) {                                            \
        int e_ = et_ * 32 + (r & 3) + ((r >> 2) << 3) + (g32 << 2);           \
        TABf[e_ * 256 + kof_] = negexp(ACC[r] + bias_[e_]);                   \
    } }

__global__ __launch_bounds__(512, 1) void fused_kernel(
    const int* __restrict__ stu_id, const int* __restrict__ exer_id,
    const float* __restrict__ kq,
    const float* __restrict__ stu_q, const float* __restrict__ exer_k,
    const float* __restrict__ stu_v, const float* __restrict__ exer_v,
    const float* __restrict__ kn,
    const float* __restrict__ W1, const float* __restrict__ b1,
    const float* __restrict__ W2, const float* __restrict__ b2,
    const float* __restrict__ W3, const float* __restrict__ b3,
    float* __restrict__ out, int B)
{
    // LDS: 128 KB, single region. Phase B: TAB fp32 [e][k-interleaved].
    // Epilogue: RED float2[8][16][64] aliased (barrier-protected).
    __shared__ float4 smem4[8192];
    float* TABf = (float*)smem4;

    const int tid  = threadIdx.x;
    const int b0   = blockIdx.x * NB;
    const int lane = tid & 63, wid = tid >> 6;
    const int l31 = lane & 31, g32 = lane >> 5;
    const int l15 = lane & 15, g16 = lane >> 4;
    const int bmax = B - 1;

    // ---- gathers for prep GEMM (scattered HBM; issue first, T14) ----
    const int bl = b0 + l15;
    const int sid_l = stu_id[bl <= bmax ? bl : bmax];
    const int eid_l = exer_id[bl <= bmax ? bl : bmax];
    float4 ga[8], ge[8];
    #pragma unroll
    for (int q = 0; q < 4; ++q) {
        int d = q * 32 + g16 * 8;
        const float4* pa = (const float4*)(stu_v + (size_t)sid_l * D + d);
        ga[2*q] = pa[0]; ga[2*q+1] = pa[1];
        const float4* pe = (const float4*)(exer_v + (size_t)eid_l * D + d);
        ge[2*q] = pe[0]; ge[2*q+1] = pe[1];
    }

    // ---- tables GEMM from global (L2-hot), wave: tbl = wid<4?1:2, et = wid&3 ----
    f32x16 t0acc = {0}, t1acc = {0}, t2acc = {0}, t3acc = {0};
    {
        const float* Wt = (wid < 4) ? W1 : W2;
        const int er = (wid & 3) * 32 + l31;
        #pragma unroll
        for (int q = 0; q < 8; ++q) {
            int del = q * 16 + g32 * 8;
            const float4* pw = (const float4*)(Wt + (size_t)er * (2 * D) + D + del);
            s16x8 a_ = pack8abs(pw[0], pw[1]);
            const float4* pk0 = (const float4*)(kn + (size_t)(  0 + l31) * D + del);
            const float4* pk1 = (const float4*)(kn + (size_t)( 32 + l31) * D + del);
            const float4* pk2 = (const float4*)(kn + (size_t)( 64 + l31) * D + del);
            const float4* pk3 = (const float4*)(kn + (size_t)( 96 + l31) * D + del);
            s16x8 f0 = pack8(pk0[0], pk0[1]);
            s16x8 f1 = pack8(pk1[0], pk1[1]);
            s16x8 f2 = pack8(pk2[0], pk2[1]);
            s16x8 f3 = pack8(pk3[0], pk3[1]);
            t0acc = __builtin_amdgcn_mfma_f32_32x32x16_bf16(a_, f0, t0acc, 0, 0, 0);
            t1acc = __builtin_amdgcn_mfma_f32_32x32x16_bf16(a_, f1, t1acc, 0, 0, 0);
            t2acc = __builtin_amdgcn_mfma_f32_32x32x16_bf16(a_, f2, t2acc, 0, 0, 0);
            t3acc = __builtin_amdgcn_mfma_f32_32x32x16_bf16(a_, f3, t3acc, 0, 0, 0);
        }
    }

    // ---- prep GEMM: C[16b x 16e], e-tile = wid  (this wave's phase-B slice) ----
    const int erow = wid * 16 + l15;
    f32x4 accS = {0, 0, 0, 0}, accE = {0, 0, 0, 0};
    #pragma unroll
    for (int q = 0; q < 4; ++q) {
        int d = q * 32 + g16 * 8;
        const float4* pb = (const float4*)(W1 + (size_t)erow * (2 * D) + d);
        accS = __builtin_amdgcn_mfma_f32_16x16x32_bf16(
            pack8(ga[2*q], ga[2*q+1]), pack8abs(pb[0], pb[1]), accS, 0, 0, 0);
        const float4* pc = (const float4*)(W2 + (size_t)erow * (2 * D) + d);
        accE = __builtin_amdgcn_mfma_f32_16x16x32_bf16(
            pack8(ge[2*q], ge[2*q+1]), pack8abs(pc[0], pc[1]), accE, 0, 0, 0);
    }
    // lane (l15=e-local, g16): holds b = g16*4+r at e = wid*16+l15
    float eS[4], eE[4], pzr[4];
    #pragma unroll
    for (int r = 0; r < 4; ++r) { eS[r] = negexp(accS[r]); eE[r] = negexp(accE[r]); }
    {
        const int e = wid * 16 + l15;
        const float w3a = fabsf(W3[e]);
        #pragma unroll
        for (int r = 0; r < 4; ++r) {
            int b = b0 + g16 * 4 + r; b = b <= bmax ? b : bmax;
            float sq = stu_q[(size_t)stu_id[b] * D + e];
            float ek = exer_k[(size_t)exer_id[b] * D + e];
            pzr[r] = sigf(sq * ek) * w3a;
        }
    }

    // ---- TAB writes (first touch of LDS -> no prior barrier needed) ----
    TWRITE(0, t0acc) TWRITE(1, t1acc) TWRITE(2, t2acc) TWRITE(3, t3acc)
    __syncthreads();   // TAB ready

    // ---------------- Phase B: wave owns e-slice [16w,16w+16), lane owns k-pair ----
    const float4* TAB4 = (const float4*)TABf;
    float2 acc[16];
    #pragma unroll
    for (int r = 0; r < 16; ++r) acc[r] = make_float2(0.f, 0.f);

    for (int jj = 0; jj < 8; ++jj) {
        const int el0 = 2 * jj, el1 = 2 * jj + 1;
        float4 t0 = TAB4[(wid * 16 + el0) * 64 + lane];   // only LDS in hot loop
        float4 t1 = TAB4[(wid * 16 + el1) * 64 + lane];
        #pragma unroll
        for (int r = 0; r < 16; ++r) {
            const int s0 = el0 + 16 * (r >> 2);           // lane holding (b=r, e=el0)
            const int s1 = el1 + 16 * (r >> 2);
            float a10 = rl(eS[r & 3], s0), a20 = rl(eE[r & 3], s0), z0 = rl(pzr[r & 3], s0);
            float a11 = rl(eS[r & 3], s1), a21 = rl(eE[r & 3], s1), z1 = rl(pzr[r & 3], s1);
            CORE(a10, a20, t0, z0, acc[r].x, acc[r].y);
            CORE(a11, a21, t1, z1, acc[r].x, acc[r].y);
        }
    }
    __syncthreads();                     // all TAB reads done -> RED may alias

    float2* RED = (float2*)TABf;         // [wave][row][lane]
    #pragma unroll
    for (int r = 0; r < 16; ++r)
        RED[(wid * 16 + r) * 64 + lane] = acc[r];
    __syncthreads();

    // ---- cross-wave reduce + epilogue: rows rA=2*wid, rB=2*wid+1 ----
    const float b3v = b3[0];
    const int rA = 2 * wid, rB = 2 * wid + 1;
    const int bA = b0 + rA, bB = b0 + rB;

    float2 sA = make_float2(0.f, 0.f), sB = make_float2(0.f, 0.f);
    #pragma unroll
    for (int w = 0; w < 8; ++w) {
        float2 pA = RED[(w * 16 + rA) * 64 + lane];
        float2 pB = RED[(w * 16 + rB) * 64 + lane];
        sA.x += pA.x; sA.y += pA.y;
        sB.x += pB.x; sB.y += pB.y;
    }

    float o0a = sigf(sA.x + b3v), o1a = sigf(sA.y + b3v);
    float o0b = sigf(sB.x + b3v), o1b = sigf(sB.y + b3v);
    float na = 0.f, da = 0.f, nb = 0.f, db = 0.f;
    if (bA < B) {
        float2 kqa = *(const float2*)(kq + (size_t)bA * D + 2 * lane);
        na = fmaf(o0a, kqa.x, o1a * kqa.y); da = kqa.x + kqa.y;
    }
    if (bB < B) {
        float2 kqb = *(const float2*)(kq + (size_t)bB * D + 2 * lane);
        nb = fmaf(o0b, kqb.x, o1b * kqb.y); db = kqb.x + kqb.y;
    }
    #pragma unroll
    for (int off = 32; off > 0; off >>= 1) {
        na += __shfl_xor(na, off); da += __shfl_xor(da, off);
        nb += __shfl_xor(nb, off); db += __shfl_xor(db, off);
    }
    if (lane == 0) {
        if (bA < B) out[bA] = na / da;
        if (bB < B) out[bB] = nb / db;
    }
}

// ---------------------------------------------------------------------------
extern "C" void kernel_launch(void* const* d_in, const int* in_sizes, int n_in,
                              void* d_out, int out_size, void* d_ws, size_t ws_size,
                              hipStream_t stream)
{
    const int*   stu_id      = (const int*)  d_in[0];
    const int*   exer_id     = (const int*)  d_in[1];
    const float* kq          = (const float*)d_in[2];
    const float* student_q   = (const float*)d_in[3];
    const float* exercise_k  = (const float*)d_in[4];
    const float* student_v   = (const float*)d_in[5];
    const float* exercise_v  = (const float*)d_in[6];
    const float* knowledge_v = (const float*)d_in[7];
    const float* W1 = (const float*)d_in[8];
    const float* b1 = (const float*)d_in[9];
    const float* W2 = (const float*)d_in[10];
    const float* b2 = (const float*)d_in[11];
    const float* W3 = (const float*)d_in[12];
    const float* b3 = (const float*)d_in[13];
    float* out = (float*)d_out;
    const int B = in_sizes[0];

    int nblk = (B + NB - 1) / NB;
    fused_kernel<<<nblk, 512, 0, stream>>>(
        stu_id, exer_id, kq, student_q, exercise_k, student_v, exercise_v,
        knowledge_v, W1, b1, W2, b2, W3, b3, out, B);
}